// Round 1
// baseline (1820.373 us; speedup 1.0000x reference)
//
#include <hip/hip_runtime.h>
#include <math.h>

#define N_NODES 50000
#define N_EDGES 800000
#define IN_F 128
#define OUT_F 256
#define EPS 1e-5f
#define BM 16   // nodes per block in fused kernel

__device__ inline float wave_reduce_sum(float v) {
    #pragma unroll
    for (int m = 32; m >= 1; m >>= 1) v += __shfl_xor(v, m, 64);
    return v;
}

// ---------------- LN1: one wave per row of 128 ----------------
__global__ __launch_bounds__(256) void ln1_kernel(const float* __restrict__ h,
        const float* __restrict__ g, const float* __restrict__ b,
        float* __restrict__ hln) {
    int wave = threadIdx.x >> 6;
    int lane = threadIdx.x & 63;
    int row = blockIdx.x * 4 + wave;
    if (row >= N_NODES) return;
    float2 v = ((const float2*)(h + (size_t)row * IN_F))[lane];
    float s  = wave_reduce_sum(v.x + v.y);
    float sq = wave_reduce_sum(v.x * v.x + v.y * v.y);
    float mu = s * (1.0f / IN_F);
    float var = sq * (1.0f / IN_F) - mu * mu;
    float rs = rsqrtf(var + EPS);
    float2 gv = ((const float2*)g)[lane];
    float2 bv = ((const float2*)b)[lane];
    float2 o;
    o.x = (v.x - mu) * rs * gv.x + bv.x;
    o.y = (v.y - mu) * rs * gv.y + bv.y;
    ((float2*)(hln + (size_t)row * IN_F))[lane] = o;
}

// ---------------- edge scatter: 32 threads per edge, float4 per thread ----------------
__global__ __launch_bounds__(256) void scatter_kernel(const float* __restrict__ hln,
        const int* __restrict__ src, const int* __restrict__ dst,
        float* __restrict__ agg, float* __restrict__ deg) {
    int tid = blockIdx.x * 256 + threadIdx.x;
    int e = tid >> 5;
    int fg = tid & 31;
    if (e >= N_EDGES) return;
    int s = src[e];
    int d = dst[e];
    float4 v = *(const float4*)(hln + (size_t)s * IN_F + fg * 4);
    float* ap = agg + (size_t)d * IN_F + fg * 4;
    atomicAdd(ap + 0, v.x);
    atomicAdd(ap + 1, v.y);
    atomicAdd(ap + 2, v.z);
    atomicAdd(ap + 3, v.w);
    if (fg == 0) atomicAdd(deg + d, 1.0f);
}

// ---------------- fused: conv + bias + repeat-skip + LN2 + selfint + ELU + residual ----------------
__global__ __launch_bounds__(256) void fused_kernel(
        const float* __restrict__ hln, const float* __restrict__ agg,
        const float* __restrict__ deg,
        const float* __restrict__ Wself, const float* __restrict__ Wneigh,
        const float* __restrict__ bneigh,
        const float* __restrict__ ln2g, const float* __restrict__ ln2b,
        const float* __restrict__ Wsi, const float* __restrict__ bsi,
        float* __restrict__ out) {
    __shared__ float sh[BM][IN_F];
    __shared__ float sm[BM][IN_F];
    __shared__ float sx[BM][OUT_F];
    __shared__ float spart[4][BM][2];

    const int t = threadIdx.x;
    const int base = blockIdx.x * BM;
    const int wave = t >> 6;

    // stage h_ln rows and mean_neigh rows into LDS (float4-coalesced)
    for (int i = t; i < BM * IN_F / 4; i += 256) {   // 512 float4s
        int r = i >> 5;          // 32 float4 per row
        int k4 = i & 31;
        ((float4*)sh[r])[k4] = ((const float4*)(hln + (size_t)(base + r) * IN_F))[k4];
        float dg = fmaxf(deg[base + r], 1.0f);
        float4 a = ((const float4*)(agg + (size_t)(base + r) * IN_F))[k4];
        float4 m; m.x = a.x / dg; m.y = a.y / dg; m.z = a.z / dg; m.w = a.w / dg;
        ((float4*)sm[r])[k4] = m;
    }
    __syncthreads();

    // phase 1: conv[:, t] = h@Wself + mean@Wneigh  (thread t owns column t, BM rows)
    float acc[BM];
    #pragma unroll
    for (int r = 0; r < BM; ++r) acc[r] = 0.f;

    for (int k = 0; k < IN_F; k += 4) {
        float w1[4], w2[4];
        #pragma unroll
        for (int i = 0; i < 4; ++i) {
            w1[i] = Wself[(size_t)(k + i) * OUT_F + t];
            w2[i] = Wneigh[(size_t)(k + i) * OUT_F + t];
        }
        #pragma unroll
        for (int r = 0; r < BM; ++r) {
            float4 hv = *(const float4*)&sh[r][k];
            float4 mv = *(const float4*)&sm[r][k];
            acc[r] += hv.x * w1[0] + hv.y * w1[1] + hv.z * w1[2] + hv.w * w1[3]
                    + mv.x * w2[0] + mv.y * w2[1] + mv.z * w2[2] + mv.w * w2[3];
        }
    }

    const float bn = bneigh[t];
    const float g2 = ln2g[t];
    const float b2 = ln2b[t];

    // conv += b_neigh + repeat(h_skip, 2): column t <- h_skip[:, t/2]
    #pragma unroll
    for (int r = 0; r < BM; ++r) acc[r] += bn + sh[r][t >> 1];

    // LN2 across the 256 columns (block-wide reduce per row)
    #pragma unroll
    for (int r = 0; r < BM; ++r) {
        float c = acc[r];
        float s  = wave_reduce_sum(c);
        float sq = wave_reduce_sum(c * c);
        if ((t & 63) == 0) { spart[wave][r][0] = s; spart[wave][r][1] = sq; }
    }
    __syncthreads();
    #pragma unroll
    for (int r = 0; r < BM; ++r) {
        float s  = spart[0][r][0] + spart[1][r][0] + spart[2][r][0] + spart[3][r][0];
        float sq = spart[0][r][1] + spart[1][r][1] + spart[2][r][1] + spart[3][r][1];
        float mu = s * (1.0f / OUT_F);
        float var = sq * (1.0f / OUT_F) - mu * mu;
        float rs = rsqrtf(var + EPS);
        sx[r][t] = (acc[r] - mu) * rs * g2 + b2;
    }
    __syncthreads();

    // phase 2: out = ELU(x @ Wsi + bsi) + x
    float acc2[BM];
    #pragma unroll
    for (int r = 0; r < BM; ++r) acc2[r] = 0.f;

    for (int k = 0; k < OUT_F; k += 4) {
        float w[4];
        #pragma unroll
        for (int i = 0; i < 4; ++i) w[i] = Wsi[(size_t)(k + i) * OUT_F + t];
        #pragma unroll
        for (int r = 0; r < BM; ++r) {
            float4 xv = *(const float4*)&sx[r][k];
            acc2[r] += xv.x * w[0] + xv.y * w[1] + xv.z * w[2] + xv.w * w[3];
        }
    }

    const float bs = bsi[t];
    #pragma unroll
    for (int r = 0; r < BM; ++r) {
        float z = acc2[r] + bs;
        float e = (z > 0.f) ? z : (expf(z) - 1.0f);
        out[(size_t)(base + r) * OUT_F + t] = e + sx[r][t];
    }
}

extern "C" void kernel_launch(void* const* d_in, const int* in_sizes, int n_in,
                              void* d_out, int out_size, void* d_ws, size_t ws_size,
                              hipStream_t stream) {
    const float* h      = (const float*)d_in[0];
    const int*   src    = (const int*)d_in[1];
    const int*   dst    = (const int*)d_in[2];
    const float* ln1g   = (const float*)d_in[3];
    const float* ln1b   = (const float*)d_in[4];
    const float* Wself  = (const float*)d_in[5];
    const float* Wneigh = (const float*)d_in[6];
    const float* bneigh = (const float*)d_in[7];
    const float* ln2g   = (const float*)d_in[8];
    const float* ln2b   = (const float*)d_in[9];
    const float* Wsi    = (const float*)d_in[10];
    const float* bsi    = (const float*)d_in[11];
    float* out = (float*)d_out;

    char* ws = (char*)d_ws;
    float* hln = (float*)(ws);                               // 50000*128*4 = 25,600,000 B
    float* agg = (float*)(ws + 25600000);                    // 25,600,000 B
    float* deg = (float*)(ws + 51200000);                    // 200,000 B

    // zero agg + deg (contiguous)
    hipMemsetAsync(ws + 25600000, 0, 25800000, stream);

    ln1_kernel<<<N_NODES / 4, 256, 0, stream>>>(h, ln1g, ln1b, hln);
    scatter_kernel<<<(N_EDGES * 32) / 256, 256, 0, stream>>>(hln, src, dst, agg, deg);
    fused_kernel<<<N_NODES / BM, 256, 0, stream>>>(hln, agg, deg, Wself, Wneigh,
                                                   bneigh, ln2g, ln2b, Wsi, bsi, out);
}

// Round 2
// 565.497 us; speedup vs baseline: 3.2191x; 3.2191x over previous
//
#include <hip/hip_runtime.h>
#include <math.h>

#define N_NODES 50000
#define N_EDGES 800000
#define IN_F 128
#define OUT_F 256
#define EPS 1e-5f
#define BM 16          // nodes per block in fused kernel
#define NSCAN 196      // ceil(50000/256)

__device__ inline float wave_reduce_sum(float v) {
    #pragma unroll
    for (int m = 32; m >= 1; m >>= 1) v += __shfl_xor(v, m, 64);
    return v;
}

// ---------------- LN1: one wave per row of 128 ----------------
__global__ __launch_bounds__(256) void ln1_kernel(const float* __restrict__ h,
        const float* __restrict__ g, const float* __restrict__ b,
        float* __restrict__ hln) {
    int wave = threadIdx.x >> 6;
    int lane = threadIdx.x & 63;
    int row = blockIdx.x * 4 + wave;
    if (row >= N_NODES) return;
    float2 v = ((const float2*)(h + (size_t)row * IN_F))[lane];
    float s  = wave_reduce_sum(v.x + v.y);
    float sq = wave_reduce_sum(v.x * v.x + v.y * v.y);
    float mu = s * (1.0f / IN_F);
    float var = sq * (1.0f / IN_F) - mu * mu;
    float rs = rsqrtf(var + EPS);
    float2 gv = ((const float2*)g)[lane];
    float2 bv = ((const float2*)b)[lane];
    float2 o;
    o.x = (v.x - mu) * rs * gv.x + bv.x;
    o.y = (v.y - mu) * rs * gv.y + bv.y;
    ((float2*)(hln + (size_t)row * IN_F))[lane] = o;
}

// ---------------- CSR build ----------------
__global__ __launch_bounds__(256) void hist_kernel(const int* __restrict__ dst,
                                                   int* __restrict__ cnt) {
    int e = blockIdx.x * 256 + threadIdx.x;
    if (e < N_EDGES) atomicAdd(&cnt[dst[e]], 1);
}

// block-local exclusive scan of cnt -> curs, block totals -> bsum
__global__ __launch_bounds__(256) void scan1_kernel(const int* __restrict__ cnt,
        int* __restrict__ curs, int* __restrict__ bsum) {
    int t = threadIdx.x;
    int i = blockIdx.x * 256 + t;
    int v = (i < N_NODES) ? cnt[i] : 0;
    int x = v;
    #pragma unroll
    for (int off = 1; off < 64; off <<= 1) {
        int y = __shfl_up(x, off, 64);
        if ((t & 63) >= off) x += y;
    }
    __shared__ int wsum[4];
    if ((t & 63) == 63) wsum[t >> 6] = x;
    __syncthreads();
    int wofs = 0;
    for (int w = 0; w < (t >> 6); ++w) wofs += wsum[w];
    int incl = x + wofs;
    if (i < N_NODES) curs[i] = incl - v;          // local exclusive
    if (t == 255) bsum[blockIdx.x] = incl;        // block total
}

// exclusive scan of NSCAN block sums in-place (single block)
__global__ __launch_bounds__(256) void scan2_kernel(int* __restrict__ bsum) {
    int t = threadIdx.x;
    int v = (t < NSCAN) ? bsum[t] : 0;
    int x = v;
    #pragma unroll
    for (int off = 1; off < 64; off <<= 1) {
        int y = __shfl_up(x, off, 64);
        if ((t & 63) >= off) x += y;
    }
    __shared__ int wsum[4];
    if ((t & 63) == 63) wsum[t >> 6] = x;
    __syncthreads();
    int wofs = 0;
    for (int w = 0; w < (t >> 6); ++w) wofs += wsum[w];
    if (t < NSCAN) bsum[t] = x + wofs - v;        // exclusive
}

__global__ __launch_bounds__(256) void scan3_kernel(int* __restrict__ curs,
        const int* __restrict__ bsum) {
    int i = blockIdx.x * 256 + threadIdx.x;
    if (i < N_NODES) curs[i] += bsum[blockIdx.x];
}

// fill CSR: eidx[segment(dst)] = src; curs[d] ends at segment end
__global__ __launch_bounds__(256) void fill_kernel(const int* __restrict__ src,
        const int* __restrict__ dst, int* __restrict__ curs, int* __restrict__ eidx) {
    int e = blockIdx.x * 256 + threadIdx.x;
    if (e >= N_EDGES) return;
    int d = dst[e];
    int pos = atomicAdd(&curs[d], 1);
    eidx[pos] = src[e];
}

// ---------------- gather segment-mean: one wave per dst node ----------------
__global__ __launch_bounds__(256) void gather_kernel(const float* __restrict__ hln,
        const int* __restrict__ cnt, const int* __restrict__ curs,
        const int* __restrict__ eidx, float* __restrict__ mean) {
    int wave = threadIdx.x >> 6;
    int lane = threadIdx.x & 63;
    int row = blockIdx.x * 4 + wave;
    if (row >= N_NODES) return;
    int deg = cnt[row];
    int end = curs[row];          // after fill, curs = segment end
    int start = end - deg;
    float2 acc = make_float2(0.f, 0.f);
    for (int j0 = 0; j0 < deg; j0 += 64) {
        int mye = (j0 + lane < deg) ? eidx[start + j0 + lane] : 0;
        int m = min(64, deg - j0);
        for (int jj = 0; jj < m; ++jj) {
            int s = __shfl(mye, jj, 64);
            float2 v = ((const float2*)(hln + (size_t)s * IN_F))[lane];
            acc.x += v.x;
            acc.y += v.y;
        }
    }
    float scale = 1.0f / fmaxf((float)deg, 1.0f);
    float2 o; o.x = acc.x * scale; o.y = acc.y * scale;
    ((float2*)(mean + (size_t)row * IN_F))[lane] = o;
}

// ---------------- fused: conv + bias + repeat-skip + LN2 + selfint + ELU + residual ----------------
__global__ __launch_bounds__(256) void fused_kernel(
        const float* __restrict__ hln, const float* __restrict__ mean,
        const float* __restrict__ Wself, const float* __restrict__ Wneigh,
        const float* __restrict__ bneigh,
        const float* __restrict__ ln2g, const float* __restrict__ ln2b,
        const float* __restrict__ Wsi, const float* __restrict__ bsi,
        float* __restrict__ out) {
    __shared__ float sh[BM][IN_F];
    __shared__ float sm[BM][IN_F];
    __shared__ float sx[BM][OUT_F];
    __shared__ float spart[4][BM][2];

    const int t = threadIdx.x;
    const int base = blockIdx.x * BM;
    const int wave = t >> 6;

    for (int i = t; i < BM * IN_F / 4; i += 256) {   // 512 float4s
        int r = i >> 5;
        int k4 = i & 31;
        ((float4*)sh[r])[k4] = ((const float4*)(hln + (size_t)(base + r) * IN_F))[k4];
        ((float4*)sm[r])[k4] = ((const float4*)(mean + (size_t)(base + r) * IN_F))[k4];
    }
    __syncthreads();

    float acc[BM];
    #pragma unroll
    for (int r = 0; r < BM; ++r) acc[r] = 0.f;

    for (int k = 0; k < IN_F; k += 4) {
        float w1[4], w2[4];
        #pragma unroll
        for (int i = 0; i < 4; ++i) {
            w1[i] = Wself[(size_t)(k + i) * OUT_F + t];
            w2[i] = Wneigh[(size_t)(k + i) * OUT_F + t];
        }
        #pragma unroll
        for (int r = 0; r < BM; ++r) {
            float4 hv = *(const float4*)&sh[r][k];
            float4 mv = *(const float4*)&sm[r][k];
            acc[r] += hv.x * w1[0] + hv.y * w1[1] + hv.z * w1[2] + hv.w * w1[3]
                    + mv.x * w2[0] + mv.y * w2[1] + mv.z * w2[2] + mv.w * w2[3];
        }
    }

    const float bn = bneigh[t];
    const float g2 = ln2g[t];
    const float b2 = ln2b[t];

    #pragma unroll
    for (int r = 0; r < BM; ++r) acc[r] += bn + sh[r][t >> 1];

    #pragma unroll
    for (int r = 0; r < BM; ++r) {
        float c = acc[r];
        float s  = wave_reduce_sum(c);
        float sq = wave_reduce_sum(c * c);
        if ((t & 63) == 0) { spart[wave][r][0] = s; spart[wave][r][1] = sq; }
    }
    __syncthreads();
    #pragma unroll
    for (int r = 0; r < BM; ++r) {
        float s  = spart[0][r][0] + spart[1][r][0] + spart[2][r][0] + spart[3][r][0];
        float sq = spart[0][r][1] + spart[1][r][1] + spart[2][r][1] + spart[3][r][1];
        float mu = s * (1.0f / OUT_F);
        float var = sq * (1.0f / OUT_F) - mu * mu;
        float rs = rsqrtf(var + EPS);
        sx[r][t] = (acc[r] - mu) * rs * g2 + b2;
    }
    __syncthreads();

    float acc2[BM];
    #pragma unroll
    for (int r = 0; r < BM; ++r) acc2[r] = 0.f;

    for (int k = 0; k < OUT_F; k += 4) {
        float w[4];
        #pragma unroll
        for (int i = 0; i < 4; ++i) w[i] = Wsi[(size_t)(k + i) * OUT_F + t];
        #pragma unroll
        for (int r = 0; r < BM; ++r) {
            float4 xv = *(const float4*)&sx[r][k];
            acc2[r] += xv.x * w[0] + xv.y * w[1] + xv.z * w[2] + xv.w * w[3];
        }
    }

    const float bs = bsi[t];
    #pragma unroll
    for (int r = 0; r < BM; ++r) {
        float z = acc2[r] + bs;
        float e = (z > 0.f) ? z : (expf(z) - 1.0f);
        out[(size_t)(base + r) * OUT_F + t] = e + sx[r][t];
    }
}

extern "C" void kernel_launch(void* const* d_in, const int* in_sizes, int n_in,
                              void* d_out, int out_size, void* d_ws, size_t ws_size,
                              hipStream_t stream) {
    const float* h      = (const float*)d_in[0];
    const int*   src    = (const int*)d_in[1];
    const int*   dst    = (const int*)d_in[2];
    const float* ln1g   = (const float*)d_in[3];
    const float* ln1b   = (const float*)d_in[4];
    const float* Wself  = (const float*)d_in[5];
    const float* Wneigh = (const float*)d_in[6];
    const float* bneigh = (const float*)d_in[7];
    const float* ln2g   = (const float*)d_in[8];
    const float* ln2b   = (const float*)d_in[9];
    const float* Wsi    = (const float*)d_in[10];
    const float* bsi    = (const float*)d_in[11];
    float* out = (float*)d_out;

    char* ws = (char*)d_ws;
    float* hln  = (float*)(ws);                        // 25,600,000 B
    float* mean = (float*)(ws + 25600000);             // 25,600,000 B
    int*   cnt  = (int*)(ws + 51200000);               //    200,000 B
    int*   curs = (int*)(ws + 51400000);               //    200,000 B
    int*   eidx = (int*)(ws + 51600000);               //  3,200,000 B
    int*   bsum = (int*)(ws + 54800000);               //        784 B

    hipMemsetAsync(cnt, 0, 200000, stream);

    ln1_kernel<<<N_NODES / 4, 256, 0, stream>>>(h, ln1g, ln1b, hln);
    hist_kernel<<<N_EDGES / 256, 256, 0, stream>>>(dst, cnt);
    scan1_kernel<<<NSCAN, 256, 0, stream>>>(cnt, curs, bsum);
    scan2_kernel<<<1, 256, 0, stream>>>(bsum);
    scan3_kernel<<<NSCAN, 256, 0, stream>>>(curs, bsum);
    fill_kernel<<<N_EDGES / 256, 256, 0, stream>>>(src, dst, curs, eidx);
    gather_kernel<<<N_NODES / 4, 256, 0, stream>>>(hln, cnt, curs, eidx, mean);
    fused_kernel<<<N_NODES / BM, 256, 0, stream>>>(hln, mean, Wself, Wneigh,
                                                   bneigh, ln2g, ln2b, Wsi, bsi, out);
}